// Round 5
// baseline (216.124 us; speedup 1.0000x reference)
//
#include <hip/hip_runtime.h>
#include <math.h>

#define NB 256     // batch
#define IC 1152    // input capsules
#define OC 10      // output capsules
#define OU 16      // output units
#define IK 8       // input units
#define KTOT (IC * IK)        // 9216 = GEMM K for s-pass
#define NTOT (OC * OU)        // 160  = GEMM N
#define S_KS 128              // s-pass K-splits
#define S_KC (KTOT / S_KS)    // 72 (= 9 input capsules per block)

// ---- prep: zero blog + transpose W -> wt2[n][k] (n-major), once per call ----
__global__ __launch_bounds__(256) void prep_kernel(
    const float* __restrict__ W,     // [1152][1280]  (i, (u? no) o*16u*8k... row = o*128+u*8+k)
    float* __restrict__ blog,        // [1152][10]
    float* __restrict__ wt2)         // [160][9216]
{
    const int i   = blockIdx.x;
    const int tid = threadIdx.x;
    __shared__ float sh[1280];

    if (i < 45) blog[i * 256 + tid] = 0.f;   // 45*256 == 11520 == IC*OC

#pragma unroll
    for (int jj = 0; jj < 5; ++jj)
        sh[jj * 256 + tid] = W[(size_t)i * 1280 + jj * 256 + tid];
    __syncthreads();

    // 320 float4 writes: q -> (n = q>>1, kq = (q&1)*4)
#pragma unroll
    for (int jj = 0; jj < 2; ++jj) {
        int q = jj * 256 + tid;
        if (q < 320) {
            int n  = q >> 1;
            int k4 = (q & 1) * 4;
            float4 g = *(const float4*)&sh[n * 8 + k4];
            *(float4*)&wt2[(size_t)n * KTOT + (size_t)i * 8 + k4] = g;
        }
    }
}

// ---- s-pass GEMM: part[ks][b][n] = sum_{k in chunk} inp[b][k]*c[i(k),o(n)]*Wt[k][n]
// grid (4 M-tiles, 128 K-splits), 256 thr. Thread tile: 8 b x 5 n. Softmax fused.
__global__ __launch_bounds__(256) void spass_kernel(
    const float* __restrict__ inp,   // [256][9216]
    const float* __restrict__ wt2,   // [160][9216]
    const float* __restrict__ blog,  // [1152][10]
    float* __restrict__ part)        // [128][256][160]
{
    const int mt  = blockIdx.x;      // b-tile
    const int ks  = blockIdx.y;      // k-split
    const int tid = threadIdx.x;
    const int mg  = tid >> 5;        // 0..7 -> b = mt*64 + mg*8 + r
    const int ln  = tid & 31;        // n = ln + 32*j
    const int b0  = mt * 64;
    const int k0  = ks * S_KC;
    const int i0  = k0 >> 3;         // 9 input capsules per block

    __shared__ float A[64][76];      // [b-local][k-local], pad 76 (19.5 KB)
    __shared__ float c_loc[9 * OC];

    // softmax rows for this block's 9 input capsules (column table)
    if (tid < 9) {
        const float* br = &blog[(size_t)(i0 + tid) * OC];
        float x[OC], m = -1e30f;
#pragma unroll
        for (int o = 0; o < OC; ++o) { x[o] = br[o]; m = fmaxf(m, x[o]); }
        float ssum = 0.f;
#pragma unroll
        for (int o = 0; o < OC; ++o) { x[o] = expf(x[o] - m); ssum += x[o]; }
        float inv = 1.f / ssum;
#pragma unroll
        for (int o = 0; o < OC; ++o) c_loc[tid * OC + o] = x[o] * inv;
    }

    // stage inp tile: 64 rows x 72 floats (18 float4/row), coalesced
#pragma unroll
    for (int jj = 0; jj < 5; ++jj) {
        int q = jj * 256 + tid;
        if (q < 64 * 18) {
            int b = q / 18, f = q - b * 18;
            float4 gv = *(const float4*)&inp[(size_t)(b0 + b) * KTOT + k0 + f * 4];
            *(float4*)&A[b][f * 4] = gv;
        }
    }
    __syncthreads();

    float acc[8][5];
#pragma unroll
    for (int r = 0; r < 8; ++r)
#pragma unroll
        for (int j = 0; j < 5; ++j) acc[r][j] = 0.f;

    // per-lane row bases into wt2 (contiguous in k)
    const float* bptr[5];
#pragma unroll
    for (int j = 0; j < 5; ++j)
        bptr[j] = wt2 + (size_t)(ln + 32 * j) * KTOT + k0;

    for (int ii = 0; ii < 9; ++ii) {
        float cj[5];
#pragma unroll
        for (int j = 0; j < 5; ++j)
            cj[j] = c_loc[ii * OC + ((ln + 32 * j) >> 4)];
#pragma unroll
        for (int kq = 0; kq < 2; ++kq) {
            const int k = ii * 8 + kq * 4;
            float4 b4[5];
#pragma unroll
            for (int j = 0; j < 5; ++j) {
                b4[j] = *(const float4*)(bptr[j] + k);     // dwordx4, per-lane stream
                b4[j].x *= cj[j]; b4[j].y *= cj[j];
                b4[j].z *= cj[j]; b4[j].w *= cj[j];
            }
#pragma unroll
            for (int r = 0; r < 8; ++r) {
                float4 a = *(const float4*)&A[mg * 8 + r][k];   // LDS broadcast
#pragma unroll
                for (int j = 0; j < 5; ++j)
                    acc[r][j] += a.x * b4[j].x + a.y * b4[j].y
                               + a.z * b4[j].z + a.w * b4[j].w;
            }
        }
    }

    float* pp = part + ((size_t)ks * NB + b0) * NTOT;
#pragma unroll
    for (int r = 0; r < 8; ++r)
#pragma unroll
        for (int j = 0; j < 5; ++j)
            pp[(size_t)(mg * 8 + r) * NTOT + ln + 32 * j] = acc[r][j];
}

// ---- reduce partials + squash -> v ---------------------------------------
__global__ __launch_bounds__(256) void reduce_squash_kernel(
    const float* __restrict__ part, float* __restrict__ vout)
{
    const int e = blockIdx.x * 256 + threadIdx.x;   // < 40960
    float a[8];
#pragma unroll
    for (int jj = 0; jj < 8; ++jj) a[jj] = 0.f;
    for (int ks = 0; ks < S_KS; ks += 8) {
#pragma unroll
        for (int jj = 0; jj < 8; ++jj)
            a[jj] += part[(size_t)(ks + jj) * (NB * NTOT) + e];
    }
    float s = ((a[0] + a[1]) + (a[2] + a[3])) + ((a[4] + a[5]) + (a[6] + a[7]));
    float sq = s * s;
    sq += __shfl_xor(sq, 1);
    sq += __shfl_xor(sq, 2);
    sq += __shfl_xor(sq, 4);
    sq += __shfl_xor(sq, 8);
    vout[e] = s * (sq / ((1.f + sq) * sqrtf(sq + 1e-9f)));
}

// ---- delta GEMM + fused W-contraction ------------------------------------
// G[(i,k)][(o,u)] = sum_b inp[b][(i,k)] * v[b][(o,u)]  (per b-split of 64)
// blog[i,o] += 1/NB * sum_{u,k} W[i,o,u,k] * G[(i,k)][(o,u)]
__global__ __launch_bounds__(256) void delta_kernel(
    const float* __restrict__ inp,   // [256][9216]
    const float* __restrict__ W,     // [1152][10][16][8]
    const float* __restrict__ v,     // [256][160]
    float* __restrict__ blog)        // [1152][10] accum
{
    const int mt  = blockIdx.x;      // m-tile: i = mt*8 + mg
    const int bs  = blockIdx.y;      // b-split
    const int tid = threadIdx.x;
    const int mg  = tid >> 5;
    const int ln  = tid & 31;
    const int m0  = mt * 64;
    const int b0  = bs * 64;

    __shared__ float A[64][68];      // [b-local][m-local], pad 68 (17.4 KB)

#pragma unroll
    for (int jj = 0; jj < 4; ++jj) {
        int q = jj * 256 + tid;
        int b = q >> 4, f = q & 15;
        float4 g = *(const float4*)&inp[(size_t)(b0 + b) * KTOT + m0 + f * 4];
        *(float4*)&A[b][f * 4] = g;
    }
    __syncthreads();

    float acc[8][5];
#pragma unroll
    for (int r = 0; r < 8; ++r)
#pragma unroll
        for (int j = 0; j < 5; ++j) acc[r][j] = 0.f;

    const float* vp = v + (size_t)b0 * NTOT + ln;

    for (int b = 0; b < 64; b += 4) {
        float bv[4][5];
#pragma unroll
        for (int kk = 0; kk < 4; ++kk)
#pragma unroll
            for (int j = 0; j < 5; ++j)
                bv[kk][j] = vp[(size_t)(b + kk) * NTOT + 32 * j];
#pragma unroll
        for (int kk = 0; kk < 4; ++kk) {
            float4 a0 = *(const float4*)&A[b + kk][mg * 8];      // broadcast
            float4 a1 = *(const float4*)&A[b + kk][mg * 8 + 4];
#pragma unroll
            for (int j = 0; j < 5; ++j) {
                acc[0][j] += a0.x * bv[kk][j];
                acc[1][j] += a0.y * bv[kk][j];
                acc[2][j] += a0.z * bv[kk][j];
                acc[3][j] += a0.w * bv[kk][j];
                acc[4][j] += a1.x * bv[kk][j];
                acc[5][j] += a1.y * bv[kk][j];
                acc[6][j] += a1.z * bv[kk][j];
                acc[7][j] += a1.w * bv[kk][j];
            }
        }
    }

    // epilogue: p[j] = sum_k W[i][o][u][k] * acc[k][j], reduce over 16 u-lanes
    const int i = mt * 8 + mg;
    float p[5];
#pragma unroll
    for (int j = 0; j < 5; ++j) {
        int n = ln + 32 * j;
        const float* wr = W + ((size_t)i * OC + (n >> 4)) * (OU * IK) + (n & 15) * IK;
        float4 w0 = *(const float4*)wr;
        float4 w1 = *(const float4*)(wr + 4);
        p[j] = w0.x * acc[0][j] + w0.y * acc[1][j] + w0.z * acc[2][j] + w0.w * acc[3][j]
             + w1.x * acc[4][j] + w1.y * acc[5][j] + w1.z * acc[6][j] + w1.w * acc[7][j];
    }
#pragma unroll
    for (int j = 0; j < 5; ++j) {
        p[j] += __shfl_xor(p[j], 1);
        p[j] += __shfl_xor(p[j], 2);
        p[j] += __shfl_xor(p[j], 4);
        p[j] += __shfl_xor(p[j], 8);
    }
    if ((tid & 15) == 0) {
#pragma unroll
        for (int j = 0; j < 5; ++j) {
            int o = (ln + 32 * j) >> 4;
            atomicAdd(&blog[(size_t)i * OC + o], p[j] * (1.0f / NB));
        }
    }
}

extern "C" void kernel_launch(void* const* d_in, const int* in_sizes, int n_in,
                              void* d_out, int out_size, void* d_ws, size_t ws_size,
                              hipStream_t stream) {
    const float* inp = (const float*)d_in[0];   // [256][1152][8]
    const float* W   = (const float*)d_in[1];   // [1152][10][16][8]
    float* vout = (float*)d_out;                // [256][10][16]

    float* blog = (float*)d_ws;                      // 11,520 floats
    float* wt2  = blog + IC * OC;                    // 1,474,560 floats
    float* part = wt2 + (size_t)KTOT * NTOT;         // 5,242,880 floats (~27 MB)

    prep_kernel<<<dim3(IC), dim3(256), 0, stream>>>(W, blog, wt2);

    for (int t = 0; t < 3; ++t) {
        spass_kernel<<<dim3(4, S_KS), dim3(256), 0, stream>>>(inp, wt2, blog, part);
        reduce_squash_kernel<<<dim3(NB * NTOT / 256), dim3(256), 0, stream>>>(part, vout);
        if (t < 2)   // final-iteration b update is dead code in the reference
            delta_kernel<<<dim3(IC / 8, 4), dim3(256), 0, stream>>>(inp, W, vout, blog);
    }
}

// Round 6
// 190.914 us; speedup vs baseline: 1.1320x; 1.1320x over previous
//
#include <hip/hip_runtime.h>
#include <math.h>

#define NB 256     // batch
#define IC 1152    // input capsules
#define OC 10      // output capsules
#define OU 16      // output units
#define IK 8       // input units
#define KTOT (IC * IK)        // 9216 = GEMM K for s-pass
#define NTOT (OC * OU)        // 160  = GEMM N
#define S_KS 64               // s-pass K-splits
#define S_KC (KTOT / S_KS)    // 144 (= 18 input capsules per block)

// ---- prep: zero blog + transpose W -> wt[k][n] (k-major), once per call ----
__global__ __launch_bounds__(256) void prep_kernel(
    const float* __restrict__ W,     // [1152][1280]  row: o*128 + u*8 + k = n*8+k
    float* __restrict__ blog,        // [1152][10]
    float* __restrict__ wt)          // [9216][160]   wt[(i*8+k)*160 + n]
{
    const int i   = blockIdx.x;
    const int tid = threadIdx.x;
    __shared__ float sh2[8 * 164];   // [k][n] transposed tile, padded

    if (i < 45) blog[i * 256 + tid] = 0.f;   // 45*256 == IC*OC

    // load W row, store transposed into LDS
#pragma unroll
    for (int jj = 0; jj < 5; ++jj) {
        int t = jj * 256 + tid;          // t = n*8 + k
        float w = W[(size_t)i * 1280 + t];
        int n = t >> 3, k = t & 7;
        sh2[k * 164 + n] = w;
    }
    __syncthreads();

    // write wt rows: t = k*160 + n, consecutive tid -> consecutive n (coalesced)
#pragma unroll
    for (int jj = 0; jj < 5; ++jj) {
        int t = jj * 256 + tid;
        int k = t / NTOT;                // 0..7
        int n = t - k * NTOT;            // 0..159
        wt[(size_t)i * 1280 + t] = sh2[k * 164 + n];
    }
}

// ---- s-pass GEMM: part[ks][b][n] = sum_{k in chunk} inp[b][k]*c[i(k),o(n)]*wt[k][n]
// grid (8 M-tiles of 32 b, 64 K-splits of 144), 256 thr. Thread: 4 b x 5 n.
__global__ __launch_bounds__(256) void spass_kernel(
    const float* __restrict__ inp,   // [256][9216]
    const float* __restrict__ wt,    // [9216][160]
    const float* __restrict__ blog,  // [1152][10]
    float* __restrict__ part)        // [64][256][160]
{
    const int mt  = blockIdx.x;      // b-tile
    const int ks  = blockIdx.y;      // k-split
    const int tid = threadIdx.x;
    const int mg  = tid >> 5;        // 0..7 -> b = mt*32 + mg*4 + r
    const int ln  = tid & 31;        // n = ln + 32*j
    const int b0  = mt * 32;
    const int k0  = ks * S_KC;
    const int i0  = ks * 18;         // 18 input capsules per block

    __shared__ float A[32][148];     // [b-local][k-local], pad 148 (18.5 KB)
    __shared__ float c_loc[18 * OC];

    // softmax rows for this block's 18 input capsules
    if (tid < 18) {
        const float* br = &blog[(size_t)(i0 + tid) * OC];
        float x[OC], m = -1e30f;
#pragma unroll
        for (int o = 0; o < OC; ++o) { x[o] = br[o]; m = fmaxf(m, x[o]); }
        float ssum = 0.f;
#pragma unroll
        for (int o = 0; o < OC; ++o) { x[o] = expf(x[o] - m); ssum += x[o]; }
        float inv = 1.f / ssum;
#pragma unroll
        for (int o = 0; o < OC; ++o) c_loc[tid * OC + o] = x[o] * inv;
    }

    // stage inp tile: 32 rows x 144 floats (36 float4/row), coalesced
#pragma unroll
    for (int jj = 0; jj < 5; ++jj) {
        int q = jj * 256 + tid;
        if (q < 32 * 36) {
            int b = q / 36, f = q - b * 36;
            float4 gv = *(const float4*)&inp[(size_t)(b0 + b) * KTOT + k0 + f * 4];
            *(float4*)&A[b][f * 4] = gv;
        }
    }
    __syncthreads();

    float acc[4][5];
#pragma unroll
    for (int r = 0; r < 4; ++r)
#pragma unroll
        for (int j = 0; j < 5; ++j) acc[r][j] = 0.f;

    const float* wtp = wt + (size_t)k0 * NTOT + ln;   // coalesced: lanes->consecutive n

    for (int ii = 0; ii < 18; ++ii) {
        float cj[5];
#pragma unroll
        for (int j = 0; j < 5; ++j)
            cj[j] = c_loc[ii * OC + ((ln + 32 * j) >> 4)];
#pragma unroll
        for (int kq = 0; kq < 2; ++kq) {
            const int k = ii * 8 + kq * 4;
            float bv[4][5];
#pragma unroll
            for (int kk = 0; kk < 4; ++kk)
#pragma unroll
                for (int j = 0; j < 5; ++j)
                    bv[kk][j] = cj[j] * wtp[(size_t)(k + kk) * NTOT + 32 * j];
#pragma unroll
            for (int r = 0; r < 4; ++r) {
                float4 a = *(const float4*)&A[mg * 4 + r][k];   // LDS broadcast
#pragma unroll
                for (int j = 0; j < 5; ++j)
                    acc[r][j] += a.x * bv[0][j] + a.y * bv[1][j]
                               + a.z * bv[2][j] + a.w * bv[3][j];
            }
        }
    }

    float* pp = part + ((size_t)ks * NB + b0) * NTOT;
#pragma unroll
    for (int r = 0; r < 4; ++r)
#pragma unroll
        for (int j = 0; j < 5; ++j)
            pp[(size_t)(mg * 4 + r) * NTOT + ln + 32 * j] = acc[r][j];
}

// ---- reduce partials + squash -> v ---------------------------------------
__global__ __launch_bounds__(256) void reduce_squash_kernel(
    const float* __restrict__ part, float* __restrict__ vout)
{
    const int e = blockIdx.x * 256 + threadIdx.x;   // < 40960
    float a[8];
#pragma unroll
    for (int jj = 0; jj < 8; ++jj) a[jj] = 0.f;
    for (int ks = 0; ks < S_KS; ks += 8) {
#pragma unroll
        for (int jj = 0; jj < 8; ++jj)
            a[jj] += part[(size_t)(ks + jj) * (NB * NTOT) + e];
    }
    float s = ((a[0] + a[1]) + (a[2] + a[3])) + ((a[4] + a[5]) + (a[6] + a[7]));
    float sq = s * s;
    sq += __shfl_xor(sq, 1);
    sq += __shfl_xor(sq, 2);
    sq += __shfl_xor(sq, 4);
    sq += __shfl_xor(sq, 8);
    vout[e] = s * (sq / ((1.f + sq) * sqrtf(sq + 1e-9f)));
}

// ---- delta GEMM + fused W-contraction ------------------------------------
// G[(i,k)][(o,u)] = sum_b inp[b][(i,k)] * v[b][(o,u)]  (per b-split of 64)
// blog[i,o] += 1/NB * sum_{u,k} W[i,o,u,k] * G[(i,k)][(o,u)]
__global__ __launch_bounds__(256) void delta_kernel(
    const float* __restrict__ inp,   // [256][9216]
    const float* __restrict__ W,     // [1152][10][16][8]
    const float* __restrict__ v,     // [256][160]
    float* __restrict__ blog)        // [1152][10] accum
{
    const int mt  = blockIdx.x;      // m-tile: i = mt*8 + mg
    const int bs  = blockIdx.y;      // b-split
    const int tid = threadIdx.x;
    const int mg  = tid >> 5;
    const int ln  = tid & 31;
    const int m0  = mt * 64;
    const int b0  = bs * 64;

    __shared__ float A[64][68];      // [b-local][m-local], pad 68 (17.4 KB)

#pragma unroll
    for (int jj = 0; jj < 4; ++jj) {
        int q = jj * 256 + tid;
        int b = q >> 4, f = q & 15;
        float4 g = *(const float4*)&inp[(size_t)(b0 + b) * KTOT + m0 + f * 4];
        *(float4*)&A[b][f * 4] = g;
    }
    __syncthreads();

    float acc[8][5];
#pragma unroll
    for (int r = 0; r < 8; ++r)
#pragma unroll
        for (int j = 0; j < 5; ++j) acc[r][j] = 0.f;

    const float* vp = v + (size_t)b0 * NTOT + ln;

    for (int b = 0; b < 64; b += 4) {
        float bv[4][5];
#pragma unroll
        for (int kk = 0; kk < 4; ++kk)
#pragma unroll
            for (int j = 0; j < 5; ++j)
                bv[kk][j] = vp[(size_t)(b + kk) * NTOT + 32 * j];
#pragma unroll
        for (int kk = 0; kk < 4; ++kk) {
            float4 a0 = *(const float4*)&A[b + kk][mg * 8];      // broadcast
            float4 a1 = *(const float4*)&A[b + kk][mg * 8 + 4];
#pragma unroll
            for (int j = 0; j < 5; ++j) {
                acc[0][j] += a0.x * bv[kk][j];
                acc[1][j] += a0.y * bv[kk][j];
                acc[2][j] += a0.z * bv[kk][j];
                acc[3][j] += a0.w * bv[kk][j];
                acc[4][j] += a1.x * bv[kk][j];
                acc[5][j] += a1.y * bv[kk][j];
                acc[6][j] += a1.z * bv[kk][j];
                acc[7][j] += a1.w * bv[kk][j];
            }
        }
    }

    // epilogue: p[j] = sum_k W[i][o][u][k] * acc[k][j], reduce over 16 u-lanes
    const int i = mt * 8 + mg;
    float p[5];
#pragma unroll
    for (int j = 0; j < 5; ++j) {
        int n = ln + 32 * j;
        const float* wr = W + ((size_t)i * OC + (n >> 4)) * (OU * IK) + (n & 15) * IK;
        float4 w0 = *(const float4*)wr;
        float4 w1 = *(const float4*)(wr + 4);
        p[j] = w0.x * acc[0][j] + w0.y * acc[1][j] + w0.z * acc[2][j] + w0.w * acc[3][j]
             + w1.x * acc[4][j] + w1.y * acc[5][j] + w1.z * acc[6][j] + w1.w * acc[7][j];
    }
#pragma unroll
    for (int j = 0; j < 5; ++j) {
        p[j] += __shfl_xor(p[j], 1);
        p[j] += __shfl_xor(p[j], 2);
        p[j] += __shfl_xor(p[j], 4);
        p[j] += __shfl_xor(p[j], 8);
    }
    if ((tid & 15) == 0) {
#pragma unroll
        for (int j = 0; j < 5; ++j) {
            int o = (ln + 32 * j) >> 4;
            atomicAdd(&blog[(size_t)i * OC + o], p[j] * (1.0f / NB));
        }
    }
}

extern "C" void kernel_launch(void* const* d_in, const int* in_sizes, int n_in,
                              void* d_out, int out_size, void* d_ws, size_t ws_size,
                              hipStream_t stream) {
    const float* inp = (const float*)d_in[0];   // [256][1152][8]
    const float* W   = (const float*)d_in[1];   // [1152][10][16][8]
    float* vout = (float*)d_out;                // [256][10][16]

    float* blog = (float*)d_ws;                      // 11,520 floats
    float* wt   = blog + IC * OC;                    // 1,474,560 floats
    float* part = wt + (size_t)KTOT * NTOT;          // 2,621,440 floats (~16 MB total)

    prep_kernel<<<dim3(IC), dim3(256), 0, stream>>>(W, blog, wt);

    for (int t = 0; t < 3; ++t) {
        spass_kernel<<<dim3(8, S_KS), dim3(256), 0, stream>>>(inp, wt, blog, part);
        reduce_squash_kernel<<<dim3(NB * NTOT / 256), dim3(256), 0, stream>>>(part, vout);
        if (t < 2)   // final-iteration b update is dead code in the reference
            delta_kernel<<<dim3(IC / 8, 4), dim3(256), 0, stream>>>(inp, W, vout, blog);
    }
}

// Round 7
// 182.725 us; speedup vs baseline: 1.1828x; 1.0448x over previous
//
#include <hip/hip_runtime.h>
#include <math.h>

#define NB 256     // batch
#define IC 1152    // input capsules
#define OC 10      // output capsules
#define OU 16      // output units
#define IK 8       // input units
#define KTOT (IC * IK)        // 9216 = GEMM K for s-pass
#define NTOT (OC * OU)        // 160  = GEMM N
#define S_KS 128              // s-pass K-splits
#define S_KC (KTOT / S_KS)    // 72 (= 9 input capsules per block)

// ---- prep: zero blog + transpose W -> wt[k][n] (k-major), once per call ----
__global__ __launch_bounds__(256) void prep_kernel(
    const float* __restrict__ W,     // [1152][1280]  row: n*8 + k
    float* __restrict__ blog,        // [1152][10]
    float* __restrict__ wt)          // [9216][160]   wt[(i*8+k)*160 + n]
{
    const int i   = blockIdx.x;
    const int tid = threadIdx.x;
    __shared__ float sh2[8 * 164];   // [k][n] transposed tile, padded

    if (i < 45) blog[i * 256 + tid] = 0.f;   // 45*256 == IC*OC

#pragma unroll
    for (int jj = 0; jj < 5; ++jj) {
        int t = jj * 256 + tid;          // t = n*8 + k
        float w = W[(size_t)i * 1280 + t];
        int n = t >> 3, k = t & 7;
        sh2[k * 164 + n] = w;
    }
    __syncthreads();

#pragma unroll
    for (int jj = 0; jj < 5; ++jj) {
        int t = jj * 256 + tid;
        int k = t / NTOT;                // 0..7
        int n = t - k * NTOT;            // 0..159
        wt[(size_t)i * 1280 + t] = sh2[k * 164 + n];
    }
}

// ---- s-pass GEMM: part[ks][b][n] = sum_{k in chunk} inp[b][k]*c[i(k),o(n)]*wt[k][n]
// grid (8 M-tiles of 32 b, 128 K-splits of 72) = 1024 blocks (4/CU).
// 256 thr: thread tile 4 b x 5 n. Softmax fused.
__global__ __launch_bounds__(256) void spass_kernel(
    const float* __restrict__ inp,   // [256][9216]
    const float* __restrict__ wt,    // [9216][160]
    const float* __restrict__ blog,  // [1152][10]
    float* __restrict__ part)        // [128][256][160]
{
    const int mt  = blockIdx.x;      // b-tile
    const int ks  = blockIdx.y;      // k-split
    const int tid = threadIdx.x;
    const int mg  = tid >> 5;        // 0..7 -> b = mt*32 + mg*4 + r
    const int ln  = tid & 31;        // n = ln + 32*j
    const int b0  = mt * 32;
    const int k0  = ks * S_KC;
    const int i0  = ks * 9;          // 9 input capsules per block

    __shared__ float A[32][76];      // [b-local][k-local], 9.7 KB
    __shared__ float c_loc[9 * OC];

    // softmax rows for this block's 9 input capsules
    if (tid < 9) {
        const float* br = &blog[(size_t)(i0 + tid) * OC];
        float x[OC], m = -1e30f;
#pragma unroll
        for (int o = 0; o < OC; ++o) { x[o] = br[o]; m = fmaxf(m, x[o]); }
        float ssum = 0.f;
#pragma unroll
        for (int o = 0; o < OC; ++o) { x[o] = expf(x[o] - m); ssum += x[o]; }
        float inv = 1.f / ssum;
#pragma unroll
        for (int o = 0; o < OC; ++o) c_loc[tid * OC + o] = x[o] * inv;
    }

    // stage inp tile: 32 rows x 72 floats = 576 float4, coalesced
#pragma unroll
    for (int jj = 0; jj < 3; ++jj) {
        int q = jj * 256 + tid;
        if (q < 32 * 18) {
            int b = q / 18, f = q - b * 18;
            float4 gv = *(const float4*)&inp[(size_t)(b0 + b) * KTOT + k0 + f * 4];
            *(float4*)&A[b][f * 4] = gv;
        }
    }
    __syncthreads();

    float acc[4][5];
#pragma unroll
    for (int r = 0; r < 4; ++r)
#pragma unroll
        for (int j = 0; j < 5; ++j) acc[r][j] = 0.f;

    const float* wtp = wt + (size_t)k0 * NTOT + ln;   // coalesced: lanes->consecutive n

    for (int ii = 0; ii < 9; ++ii) {
        float cj[5];
#pragma unroll
        for (int j = 0; j < 5; ++j)
            cj[j] = c_loc[ii * OC + ((ln + 32 * j) >> 4)];
#pragma unroll
        for (int kq = 0; kq < 2; ++kq) {
            const int k = ii * 8 + kq * 4;
            float bv[4][5];
#pragma unroll
            for (int kk = 0; kk < 4; ++kk)
#pragma unroll
                for (int j = 0; j < 5; ++j)
                    bv[kk][j] = cj[j] * wtp[(size_t)(k + kk) * NTOT + 32 * j];
#pragma unroll
            for (int r = 0; r < 4; ++r) {
                float4 a = *(const float4*)&A[mg * 4 + r][k];   // LDS broadcast
#pragma unroll
                for (int j = 0; j < 5; ++j)
                    acc[r][j] += a.x * bv[0][j] + a.y * bv[1][j]
                               + a.z * bv[2][j] + a.w * bv[3][j];
            }
        }
    }

    float* pp = part + ((size_t)ks * NB + b0) * NTOT;
#pragma unroll
    for (int r = 0; r < 4; ++r)
#pragma unroll
        for (int j = 0; j < 5; ++j)
            pp[(size_t)(mg * 4 + r) * NTOT + ln + 32 * j] = acc[r][j];
}

// ---- reduce partials + squash -> v ---------------------------------------
// block = 256 thr = 32 e-lanes x 8 ks-groups (16 slices each); 1280 blocks.
__global__ __launch_bounds__(256) void reduce_squash_kernel(
    const float* __restrict__ part, float* __restrict__ vout)
{
    const int tid = threadIdx.x;
    const int el  = tid & 31;
    const int kl  = tid >> 5;        // 0..7
    const int e   = blockIdx.x * 32 + el;   // < 40960

    float a = 0.f;
#pragma unroll
    for (int s = 0; s < 16; ++s)
        a += part[(size_t)(kl * 16 + s) * (NB * NTOT) + e];

    __shared__ float red[8][36];
    red[kl][el] = a;
    __syncthreads();

    if (tid < 32) {
        float s = ((red[0][el] + red[1][el]) + (red[2][el] + red[3][el]))
                + ((red[4][el] + red[5][el]) + (red[6][el] + red[7][el]));
        float sq = s * s;
        sq += __shfl_xor(sq, 1);
        sq += __shfl_xor(sq, 2);
        sq += __shfl_xor(sq, 4);
        sq += __shfl_xor(sq, 8);
        vout[e] = s * (sq / ((1.f + sq) * sqrtf(sq + 1e-9f)));
    }
}

// ---- delta GEMM + fused W-contraction ------------------------------------
// G[(i,k)][(o,u)] = sum_b inp[b][(i,k)] * v[b][(o,u)]  (per b-split of 32)
// blog[i,o] += 1/NB * sum_{u,k} W[i,o,u,k] * G[(i,k)][(o,u)]
// grid (144 m-tiles, 8 b-splits) = 1152 blocks (4.5/CU).
__global__ __launch_bounds__(256) void delta_kernel(
    const float* __restrict__ inp,   // [256][9216]
    const float* __restrict__ W,     // [1152][10][16][8]
    const float* __restrict__ v,     // [256][160]
    float* __restrict__ blog)        // [1152][10] accum
{
    const int mt  = blockIdx.x;      // m-tile: i = mt*8 + mg
    const int bs  = blockIdx.y;      // b-split
    const int tid = threadIdx.x;
    const int mg  = tid >> 5;
    const int ln  = tid & 31;
    const int m0  = mt * 64;
    const int b0  = bs * 32;

    __shared__ float A[32][68];      // [b-local][m-local], 8.7 KB

#pragma unroll
    for (int jj = 0; jj < 2; ++jj) {
        int q = jj * 256 + tid;
        int b = q >> 4, f = q & 15;
        float4 g = *(const float4*)&inp[(size_t)(b0 + b) * KTOT + m0 + f * 4];
        *(float4*)&A[b][f * 4] = g;
    }
    __syncthreads();

    float acc[8][5];
#pragma unroll
    for (int r = 0; r < 8; ++r)
#pragma unroll
        for (int j = 0; j < 5; ++j) acc[r][j] = 0.f;

    const float* vp = v + (size_t)b0 * NTOT + ln;

    for (int b = 0; b < 32; b += 4) {
        float bv[4][5];
#pragma unroll
        for (int kk = 0; kk < 4; ++kk)
#pragma unroll
            for (int j = 0; j < 5; ++j)
                bv[kk][j] = vp[(size_t)(b + kk) * NTOT + 32 * j];
#pragma unroll
        for (int kk = 0; kk < 4; ++kk) {
            float4 a0 = *(const float4*)&A[b + kk][mg * 8];      // broadcast
            float4 a1 = *(const float4*)&A[b + kk][mg * 8 + 4];
#pragma unroll
            for (int j = 0; j < 5; ++j) {
                acc[0][j] += a0.x * bv[kk][j];
                acc[1][j] += a0.y * bv[kk][j];
                acc[2][j] += a0.z * bv[kk][j];
                acc[3][j] += a0.w * bv[kk][j];
                acc[4][j] += a1.x * bv[kk][j];
                acc[5][j] += a1.y * bv[kk][j];
                acc[6][j] += a1.z * bv[kk][j];
                acc[7][j] += a1.w * bv[kk][j];
            }
        }
    }

    // epilogue: p[j] = sum_k W[i][o][u][k] * acc[k][j], reduce over 16 u-lanes
    const int i = mt * 8 + mg;
    float p[5];
#pragma unroll
    for (int j = 0; j < 5; ++j) {
        int n = ln + 32 * j;
        const float* wr = W + ((size_t)i * OC + (n >> 4)) * (OU * IK) + (n & 15) * IK;
        float4 w0 = *(const float4*)wr;
        float4 w1 = *(const float4*)(wr + 4);
        p[j] = w0.x * acc[0][j] + w0.y * acc[1][j] + w0.z * acc[2][j] + w0.w * acc[3][j]
             + w1.x * acc[4][j] + w1.y * acc[5][j] + w1.z * acc[6][j] + w1.w * acc[7][j];
    }
#pragma unroll
    for (int j = 0; j < 5; ++j) {
        p[j] += __shfl_xor(p[j], 1);
        p[j] += __shfl_xor(p[j], 2);
        p[j] += __shfl_xor(p[j], 4);
        p[j] += __shfl_xor(p[j], 8);
    }
    if ((tid & 15) == 0) {
#pragma unroll
        for (int j = 0; j < 5; ++j) {
            int o = (ln + 32 * j) >> 4;
            atomicAdd(&blog[(size_t)i * OC + o], p[j] * (1.0f / NB));
        }
    }
}

extern "C" void kernel_launch(void* const* d_in, const int* in_sizes, int n_in,
                              void* d_out, int out_size, void* d_ws, size_t ws_size,
                              hipStream_t stream) {
    const float* inp = (const float*)d_in[0];   // [256][1152][8]
    const float* W   = (const float*)d_in[1];   // [1152][10][16][8]
    float* vout = (float*)d_out;                // [256][10][16]

    float* blog = (float*)d_ws;                      // 11,520 floats
    float* wt   = blog + IC * OC;                    // 1,474,560 floats
    float* part = wt + (size_t)KTOT * NTOT;          // 5,242,880 floats (~27 MB)

    prep_kernel<<<dim3(IC), dim3(256), 0, stream>>>(W, blog, wt);

    for (int t = 0; t < 3; ++t) {
        spass_kernel<<<dim3(8, S_KS), dim3(256), 0, stream>>>(inp, wt, blog, part);
        reduce_squash_kernel<<<dim3(NB * NTOT / 32), dim3(256), 0, stream>>>(part, vout);
        if (t < 2)   // final-iteration b update is dead code in the reference
            delta_kernel<<<dim3(IC / 8, 8), dim3(256), 0, stream>>>(inp, W, vout, blog);
    }
}

// Round 8
// 163.483 us; speedup vs baseline: 1.3220x; 1.1177x over previous
//
#include <hip/hip_runtime.h>
#include <math.h>

#define NB 256     // batch
#define IC 1152    // input capsules
#define OC 10      // output capsules
#define OU 16      // output units
#define IK 8       // input units
#define KTOT (IC * IK)        // 9216
#define NTOT (OC * OU)        // 160
#define S_KS 16               // s-pass K-splits (576 k = 18 MFMA each)

typedef __attribute__((ext_vector_type(8))) short short8;
typedef __attribute__((ext_vector_type(4))) float f32x4;

static __device__ __forceinline__ unsigned short f2bf(float f) {
    unsigned u = __float_as_uint(f);
    unsigned r = (u + 0x7FFF + ((u >> 16) & 1)) >> 16;   // RNE
    return (unsigned short)r;
}

// ---- prep: zero blog + convert inp -> bf16 [256][9216], once per call ----
__global__ __launch_bounds__(256) void prep_kernel(
    const float* __restrict__ inp,
    float* __restrict__ blog,
    unsigned short* __restrict__ inpb)
{
    const int bid = blockIdx.x, tid = threadIdx.x;
    if (bid < 45) blog[bid * 256 + tid] = 0.f;

    size_t off = (size_t)bid * 2048 + tid * 8;
    float4 a = *(const float4*)&inp[off];
    float4 b = *(const float4*)&inp[off + 4];
    union { short8 v; unsigned short u[8]; } pk;
    pk.u[0] = f2bf(a.x); pk.u[1] = f2bf(a.y); pk.u[2] = f2bf(a.z); pk.u[3] = f2bf(a.w);
    pk.u[4] = f2bf(b.x); pk.u[5] = f2bf(b.y); pk.u[6] = f2bf(b.z); pk.u[7] = f2bf(b.w);
    *(short8*)&inpb[off] = pk.v;
}

// ---- wc: softmax(blog) folded into W, bf16, layout wcT[n][k] (k contiguous) ----
__global__ __launch_bounds__(256) void wc_kernel(
    const float* __restrict__ W,     // [1152][1280]  row: n*8 + k
    const float* __restrict__ blog,  // [1152][10]
    unsigned short* __restrict__ wct)// [160][9216]
{
    const int i = blockIdx.x, tid = threadIdx.x;
    __shared__ float c_sh[OC];
    if (tid < OC) {
        const float* br = &blog[(size_t)i * OC];
        float x[OC], m = -1e30f;
#pragma unroll
        for (int o = 0; o < OC; ++o) { x[o] = br[o]; m = fmaxf(m, x[o]); }
        float ssum = 0.f;
#pragma unroll
        for (int o = 0; o < OC; ++o) ssum += expf(x[o] - m);
        c_sh[tid] = expf(x[tid] - m) / ssum;
    }
    __syncthreads();
    if (tid < NTOT) {
        const float cc = c_sh[tid >> 4];
        const float* wr = &W[(size_t)i * 1280 + tid * 8];
        float4 a = *(const float4*)wr;
        float4 b = *(const float4*)(wr + 4);
        union { short8 v; unsigned short u[8]; } pk;
        pk.u[0] = f2bf(cc * a.x); pk.u[1] = f2bf(cc * a.y);
        pk.u[2] = f2bf(cc * a.z); pk.u[3] = f2bf(cc * a.w);
        pk.u[4] = f2bf(cc * b.x); pk.u[5] = f2bf(cc * b.y);
        pk.u[6] = f2bf(cc * b.z); pk.u[7] = f2bf(cc * b.w);
        *(short8*)&wct[(size_t)tid * KTOT + (size_t)i * 8] = pk.v;
    }
}

// ---- s-pass via MFMA: part[ks][b][n] += inp_bf16 @ wcT over k-chunk ----
// 640 blocks x 256 thr = 2560 waves; wave g: ks = g&15, mt = (g>>4)&15, nt = g>>8.
__global__ __launch_bounds__(256) void spass_kernel(
    const unsigned short* __restrict__ inpb,  // [256][9216]
    const unsigned short* __restrict__ wct,   // [160][9216]
    float* __restrict__ part)                 // [16][256][160]
{
    const int g    = blockIdx.x * 4 + (threadIdx.x >> 6);
    const int lane = threadIdx.x & 63;
    const int ks   = g & 15;
    const int mt   = (g >> 4) & 15;
    const int nt   = g >> 8;            // 0..9
    const int l15  = lane & 15;
    const int koff = (lane >> 4) * 8;
    const int k0   = ks * 576;

    const unsigned short* ap = inpb + (size_t)(mt * 16 + l15) * KTOT + k0 + koff;
    const unsigned short* bp = wct  + (size_t)(nt * 16 + l15) * KTOT + k0 + koff;

    f32x4 acc = {0.f, 0.f, 0.f, 0.f};
#pragma unroll
    for (int kk = 0; kk < 18; ++kk) {
        short8 av = *(const short8*)(ap + kk * 32);
        short8 bv = *(const short8*)(bp + kk * 32);
        acc = __builtin_amdgcn_mfma_f32_16x16x32_bf16(av, bv, acc, 0, 0, 0);
    }

    float* pp = part + ((size_t)ks * NB + mt * 16 + (lane >> 4) * 4) * NTOT + nt * 16 + l15;
#pragma unroll
    for (int r = 0; r < 4; ++r)
        pp[(size_t)r * NTOT] = acc[r];
}

// ---- reduce partials + squash -> v ---------------------------------------
// block = 256 thr = 32 e-lanes x 8 ks-groups (2 slices each); 1280 blocks.
__global__ __launch_bounds__(256) void reduce_squash_kernel(
    const float* __restrict__ part, float* __restrict__ vout)
{
    const int tid = threadIdx.x;
    const int el  = tid & 31;
    const int kl  = tid >> 5;        // 0..7
    const int e   = blockIdx.x * 32 + el;

    float a = part[(size_t)(kl * 2) * (NB * NTOT) + e]
            + part[(size_t)(kl * 2 + 1) * (NB * NTOT) + e];

    __shared__ float red[8][36];
    red[kl][el] = a;
    __syncthreads();

    if (tid < 32) {
        float s = ((red[0][el] + red[1][el]) + (red[2][el] + red[3][el]))
                + ((red[4][el] + red[5][el]) + (red[6][el] + red[7][el]));
        float sq = s * s;
        sq += __shfl_xor(sq, 1);
        sq += __shfl_xor(sq, 2);
        sq += __shfl_xor(sq, 4);
        sq += __shfl_xor(sq, 8);
        vout[e] = s * (sq / ((1.f + sq) * sqrtf(sq + 1e-9f)));
    }
}

// ---- delta GEMM + fused W-contraction (fp32, proven R7 body) -------------
__global__ __launch_bounds__(256) void delta_kernel(
    const float* __restrict__ inp,   // [256][9216]
    const float* __restrict__ W,     // [1152][10][16][8]
    const float* __restrict__ v,     // [256][160]
    float* __restrict__ blog)        // [1152][10] accum
{
    const int mt  = blockIdx.x;
    const int bs  = blockIdx.y;
    const int tid = threadIdx.x;
    const int mg  = tid >> 5;
    const int ln  = tid & 31;
    const int m0  = mt * 64;
    const int b0  = bs * 32;

    __shared__ float A[32][68];

#pragma unroll
    for (int jj = 0; jj < 2; ++jj) {
        int q = jj * 256 + tid;
        int b = q >> 4, f = q & 15;
        float4 g = *(const float4*)&inp[(size_t)(b0 + b) * KTOT + m0 + f * 4];
        *(float4*)&A[b][f * 4] = g;
    }
    __syncthreads();

    float acc[8][5];
#pragma unroll
    for (int r = 0; r < 8; ++r)
#pragma unroll
        for (int j = 0; j < 5; ++j) acc[r][j] = 0.f;

    const float* vp = v + (size_t)b0 * NTOT + ln;

    for (int b = 0; b < 32; b += 4) {
        float bv[4][5];
#pragma unroll
        for (int kk = 0; kk < 4; ++kk)
#pragma unroll
            for (int j = 0; j < 5; ++j)
                bv[kk][j] = vp[(size_t)(b + kk) * NTOT + 32 * j];
#pragma unroll
        for (int kk = 0; kk < 4; ++kk) {
            float4 a0 = *(const float4*)&A[b + kk][mg * 8];
            float4 a1 = *(const float4*)&A[b + kk][mg * 8 + 4];
#pragma unroll
            for (int j = 0; j < 5; ++j) {
                acc[0][j] += a0.x * bv[kk][j];
                acc[1][j] += a0.y * bv[kk][j];
                acc[2][j] += a0.z * bv[kk][j];
                acc[3][j] += a0.w * bv[kk][j];
                acc[4][j] += a1.x * bv[kk][j];
                acc[5][j] += a1.y * bv[kk][j];
                acc[6][j] += a1.z * bv[kk][j];
                acc[7][j] += a1.w * bv[kk][j];
            }
        }
    }

    const int i = mt * 8 + mg;
    float p[5];
#pragma unroll
    for (int j = 0; j < 5; ++j) {
        int n = ln + 32 * j;
        const float* wr = W + ((size_t)i * OC + (n >> 4)) * (OU * IK) + (n & 15) * IK;
        float4 w0 = *(const float4*)wr;
        float4 w1 = *(const float4*)(wr + 4);
        p[j] = w0.x * acc[0][j] + w0.y * acc[1][j] + w0.z * acc[2][j] + w0.w * acc[3][j]
             + w1.x * acc[4][j] + w1.y * acc[5][j] + w1.z * acc[6][j] + w1.w * acc[7][j];
    }
#pragma unroll
    for (int j = 0; j < 5; ++j) {
        p[j] += __shfl_xor(p[j], 1);
        p[j] += __shfl_xor(p[j], 2);
        p[j] += __shfl_xor(p[j], 4);
        p[j] += __shfl_xor(p[j], 8);
    }
    if ((tid & 15) == 0) {
#pragma unroll
        for (int j = 0; j < 5; ++j) {
            int o = (ln + 32 * j) >> 4;
            atomicAdd(&blog[(size_t)i * OC + o], p[j] * (1.0f / NB));
        }
    }
}

extern "C" void kernel_launch(void* const* d_in, const int* in_sizes, int n_in,
                              void* d_out, int out_size, void* d_ws, size_t ws_size,
                              hipStream_t stream) {
    const float* inp = (const float*)d_in[0];   // [256][1152][8]
    const float* W   = (const float*)d_in[1];   // [1152][10][16][8]
    float* vout = (float*)d_out;                // [256][10][16]

    float* blog = (float*)d_ws;                              // 11,520 f
    float* part = blog + IC * OC;                            // 655,360 f
    unsigned short* inpb = (unsigned short*)(part + (size_t)S_KS * NB * NTOT);
    unsigned short* wct  = inpb + (size_t)NB * KTOT;         // 1,474,560 u16

    prep_kernel<<<dim3(IC), dim3(256), 0, stream>>>(inp, blog, inpb);

    for (int t = 0; t < 3; ++t) {
        wc_kernel<<<dim3(IC), dim3(256), 0, stream>>>(W, blog, wct);
        spass_kernel<<<dim3(640), dim3(256), 0, stream>>>(inpb, wct, part);
        reduce_squash_kernel<<<dim3(NB * NTOT / 32), dim3(256), 0, stream>>>(part, vout);
        if (t < 2)   // final-iteration b update is dead code in the reference
            delta_kernel<<<dim3(IC / 8, 8), dim3(256), 0, stream>>>(inp, W, vout, blog);
    }
}

// Round 9
// 158.307 us; speedup vs baseline: 1.3652x; 1.0327x over previous
//
#include <hip/hip_runtime.h>
#include <math.h>

#define NB 256     // batch
#define IC 1152    // input capsules
#define OC 10      // output capsules
#define OU 16      // output units
#define IK 8       // input units
#define KTOT (IC * IK)        // 9216
#define NTOT (OC * OU)        // 160
#define S_KS 16               // s-pass K-splits (576 k = 18 MFMA each)

typedef __attribute__((ext_vector_type(8))) short short8;
typedef __attribute__((ext_vector_type(4))) float f32x4;

static __device__ __forceinline__ unsigned short f2bf(float f) {
    unsigned u = __float_as_uint(f);
    unsigned r = (u + 0x7FFF + ((u >> 16) & 1)) >> 16;   // RNE
    return (unsigned short)r;
}

// ---- prep: zero blog + inp -> bf16 [256][9216] AND bf16 transpose [9216][256]
// grid (144 k-tiles of 64, 4 b-tiles of 64), 256 thr, LDS 64x65 tile.
__global__ __launch_bounds__(256) void prep_kernel(
    const float* __restrict__ inp,
    float* __restrict__ blog,
    unsigned short* __restrict__ inpb,   // [256][9216]
    unsigned short* __restrict__ inpT)   // [9216][256]
{
    const int kt  = blockIdx.x;      // 0..143
    const int bt  = blockIdx.y;      // 0..3
    const int tid = threadIdx.x;

    {
        int bid = blockIdx.y * 144 + blockIdx.x;
        if (bid < 45) blog[bid * 256 + tid] = 0.f;
    }

    __shared__ unsigned short sh[64][65];

#pragma unroll
    for (int j = 0; j < 4; ++j) {
        int q     = j * 256 + tid;
        int b_loc = q >> 4;
        int kq    = (q & 15) * 4;
        float4 g = *(const float4*)&inp[(size_t)(bt * 64 + b_loc) * KTOT + kt * 64 + kq];
        unsigned short h0 = f2bf(g.x), h1 = f2bf(g.y), h2 = f2bf(g.z), h3 = f2bf(g.w);
        sh[kq][b_loc] = h0; sh[kq + 1][b_loc] = h1;
        sh[kq + 2][b_loc] = h2; sh[kq + 3][b_loc] = h3;
        short4 pk = { (short)h0, (short)h1, (short)h2, (short)h3 };
        *(short4*)&inpb[(size_t)(bt * 64 + b_loc) * KTOT + kt * 64 + kq] = pk;
    }
    __syncthreads();

#pragma unroll
    for (int j = 0; j < 4; ++j) {
        int q     = j * 256 + tid;
        int k_loc = q >> 4;
        int b4    = (q & 15) * 4;
        short4 pk = { (short)sh[k_loc][b4],     (short)sh[k_loc][b4 + 1],
                      (short)sh[k_loc][b4 + 2], (short)sh[k_loc][b4 + 3] };
        *(short4*)&inpT[(size_t)(kt * 64 + k_loc) * 256 + bt * 64 + b4] = pk;
    }
}

// ---- wc: softmax(blog) folded into W, bf16, layout wcT[n][k] (k contiguous) ----
__global__ __launch_bounds__(256) void wc_kernel(
    const float* __restrict__ W,     // [1152][1280]  row: n*8 + k
    const float* __restrict__ blog,  // [1152][10]
    unsigned short* __restrict__ wct)// [160][9216]
{
    const int i = blockIdx.x, tid = threadIdx.x;
    __shared__ float c_sh[OC];
    if (tid < OC) {
        const float* br = &blog[(size_t)i * OC];
        float x[OC], m = -1e30f;
#pragma unroll
        for (int o = 0; o < OC; ++o) { x[o] = br[o]; m = fmaxf(m, x[o]); }
        float ssum = 0.f;
#pragma unroll
        for (int o = 0; o < OC; ++o) ssum += expf(x[o] - m);
        c_sh[tid] = expf(x[tid] - m) / ssum;
    }
    __syncthreads();
    if (tid < NTOT) {
        const float cc = c_sh[tid >> 4];
        const float* wr = &W[(size_t)i * 1280 + tid * 8];
        float4 a = *(const float4*)wr;
        float4 b = *(const float4*)(wr + 4);
        union { short8 v; unsigned short u[8]; } pk;
        pk.u[0] = f2bf(cc * a.x); pk.u[1] = f2bf(cc * a.y);
        pk.u[2] = f2bf(cc * a.z); pk.u[3] = f2bf(cc * a.w);
        pk.u[4] = f2bf(cc * b.x); pk.u[5] = f2bf(cc * b.y);
        pk.u[6] = f2bf(cc * b.z); pk.u[7] = f2bf(cc * b.w);
        *(short8*)&wct[(size_t)tid * KTOT + (size_t)i * 8] = pk.v;
    }
}

// ---- s-pass via MFMA: part[ks][b][n] += inp_bf16 @ wcT over k-chunk ----
__global__ __launch_bounds__(256) void spass_kernel(
    const unsigned short* __restrict__ inpb,  // [256][9216]
    const unsigned short* __restrict__ wct,   // [160][9216]
    float* __restrict__ part)                 // [16][256][160]
{
    const int g    = blockIdx.x * 4 + (threadIdx.x >> 6);
    const int lane = threadIdx.x & 63;
    const int ks   = g & 15;
    const int mt   = (g >> 4) & 15;
    const int nt   = g >> 8;            // 0..9
    const int l15  = lane & 15;
    const int koff = (lane >> 4) * 8;
    const int k0   = ks * 576;

    const unsigned short* ap = inpb + (size_t)(mt * 16 + l15) * KTOT + k0 + koff;
    const unsigned short* bp = wct  + (size_t)(nt * 16 + l15) * KTOT + k0 + koff;

    f32x4 acc = {0.f, 0.f, 0.f, 0.f};
#pragma unroll
    for (int kk = 0; kk < 18; ++kk) {
        short8 av = *(const short8*)(ap + kk * 32);
        short8 bv = *(const short8*)(bp + kk * 32);
        acc = __builtin_amdgcn_mfma_f32_16x16x32_bf16(av, bv, acc, 0, 0, 0);
    }

    float* pp = part + ((size_t)ks * NB + mt * 16 + (lane >> 4) * 4) * NTOT + nt * 16 + l15;
#pragma unroll
    for (int r = 0; r < 4; ++r)
        pp[(size_t)r * NTOT] = acc[r];
}

// ---- reduce partials + squash -> v (fp32) and vT (bf16, transposed) ------
__global__ __launch_bounds__(256) void reduce_squash_kernel(
    const float* __restrict__ part, float* __restrict__ vout,
    unsigned short* __restrict__ vT)   // [160][256]
{
    const int tid = threadIdx.x;
    const int el  = tid & 31;
    const int kl  = tid >> 5;        // 0..7
    const int e   = blockIdx.x * 32 + el;

    float a = part[(size_t)(kl * 2) * (NB * NTOT) + e]
            + part[(size_t)(kl * 2 + 1) * (NB * NTOT) + e];

    __shared__ float red[8][36];
    red[kl][el] = a;
    __syncthreads();

    if (tid < 32) {
        float s = ((red[0][el] + red[1][el]) + (red[2][el] + red[3][el]))
                + ((red[4][el] + red[5][el]) + (red[6][el] + red[7][el]));
        float sq = s * s;
        sq += __shfl_xor(sq, 1);
        sq += __shfl_xor(sq, 2);
        sq += __shfl_xor(sq, 4);
        sq += __shfl_xor(sq, 8);
        float vv = s * (sq / ((1.f + sq) * sqrtf(sq + 1e-9f)));
        vout[e] = vv;
        int n = e % NTOT, b = e / NTOT;
        vT[(size_t)n * 256 + b] = f2bf(vv);
    }
}

// ---- delta via MFMA: G[ik][ou] = sum_b inpT[ik][b]*vT[ou][b], fused W-contraction
// 5760 wave-tiles (576 mt x 10 nt) = 1440 blocks. K=256 in-wave (8 MFMA).
// Each (i,o) has exactly one writer -> plain RMW on blog, no atomics.
__global__ __launch_bounds__(256) void delta_kernel(
    const unsigned short* __restrict__ inpT,  // [9216][256]
    const unsigned short* __restrict__ vT,    // [160][256]
    const float* __restrict__ W,              // [1152][10][16][8]
    float* __restrict__ blog)                 // [1152][10] accum
{
    const int g    = blockIdx.x * 4 + (threadIdx.x >> 6);
    const int lane = threadIdx.x & 63;
    const int mt   = g % 576;
    const int nt   = g / 576;           // = o
    const int l15  = lane & 15;
    const int quad = lane >> 4;
    const int koff = quad * 8;

    const unsigned short* ap = inpT + (size_t)(mt * 16 + l15) * 256 + koff;
    const unsigned short* bp = vT   + (size_t)(nt * 16 + l15) * 256 + koff;

    f32x4 acc = {0.f, 0.f, 0.f, 0.f};
#pragma unroll
    for (int kk = 0; kk < 8; ++kk) {
        short8 av = *(const short8*)(ap + kk * 32);
        short8 bv = *(const short8*)(bp + kk * 32);
        acc = __builtin_amdgcn_mfma_f32_16x16x32_bf16(av, bv, acc, 0, 0, 0);
    }

    // lane holds G[m=quad*4+r][n=l15]; m -> i_loc = quad>>1, k = (quad&1)*4+r; n -> u
    const int i = mt * 2 + (quad >> 1);
    const float* wr = W + (((size_t)i * OC + nt) * OU + l15) * IK + (quad & 1) * 4;
    float4 wf = *(const float4*)wr;
    float wsum = wf.x * acc[0] + wf.y * acc[1] + wf.z * acc[2] + wf.w * acc[3];

    wsum += __shfl_xor(wsum, 16);   // combine the two quads of this i
    wsum += __shfl_xor(wsum, 1);    // reduce over u (16 lanes)
    wsum += __shfl_xor(wsum, 2);
    wsum += __shfl_xor(wsum, 4);
    wsum += __shfl_xor(wsum, 8);

    if ((lane & 31) == 0)
        blog[(size_t)i * OC + nt] += wsum * (1.0f / NB);
}

extern "C" void kernel_launch(void* const* d_in, const int* in_sizes, int n_in,
                              void* d_out, int out_size, void* d_ws, size_t ws_size,
                              hipStream_t stream) {
    const float* inp = (const float*)d_in[0];   // [256][1152][8]
    const float* W   = (const float*)d_in[1];   // [1152][10][16][8]
    float* vout = (float*)d_out;                // [256][10][16]

    float* blog = (float*)d_ws;                              // 11,520 f
    float* part = blog + IC * OC;                            // 655,360 f
    unsigned short* inpb = (unsigned short*)(part + (size_t)S_KS * NB * NTOT);
    unsigned short* wct  = inpb + (size_t)NB * KTOT;         // 1,474,560 u16
    unsigned short* inpT = wct + (size_t)NTOT * KTOT;        // 2,359,296 u16
    unsigned short* vT   = inpT + (size_t)KTOT * 256;        // 40,960 u16

    prep_kernel<<<dim3(144, 4), dim3(256), 0, stream>>>(inp, blog, inpb, inpT);

    for (int t = 0; t < 3; ++t) {
        wc_kernel<<<dim3(IC), dim3(256), 0, stream>>>(W, blog, wct);
        spass_kernel<<<dim3(640), dim3(256), 0, stream>>>(inpb, wct, part);
        reduce_squash_kernel<<<dim3(NB * NTOT / 32), dim3(256), 0, stream>>>(part, vout, vT);
        if (t < 2)   // final-iteration b update is dead code in the reference
            delta_kernel<<<dim3(1440), dim3(256), 0, stream>>>(inpT, vT, W, blog);
    }
}

// Round 10
// 132.810 us; speedup vs baseline: 1.6273x; 1.1920x over previous
//
#include <hip/hip_runtime.h>
#include <math.h>

#define NB 256     // batch
#define IC 1152    // input capsules
#define OC 10      // output capsules
#define OU 16      // output units
#define IK 8       // input units
#define KTOT (IC * IK)        // 9216
#define NTOT (OC * OU)        // 160
#define S_KS 16               // s-pass K-splits (576 k = 18 MFMA each)

typedef __attribute__((ext_vector_type(8))) short short8;
typedef __attribute__((ext_vector_type(4))) float f32x4;

static __device__ __forceinline__ unsigned short f2bf(float f) {
    unsigned u = __float_as_uint(f);
    unsigned r = (u + 0x7FFF + ((u >> 16) & 1)) >> 16;   // RNE
    return (unsigned short)r;
}

// ---- prep: zero blog + inp -> bf16 [256][9216] AND bf16 transpose [9216][256]
__global__ __launch_bounds__(256) void prep_kernel(
    const float* __restrict__ inp,
    float* __restrict__ blog,
    unsigned short* __restrict__ inpb,   // [256][9216]
    unsigned short* __restrict__ inpT)   // [9216][256]
{
    const int kt  = blockIdx.x;      // 0..143
    const int bt  = blockIdx.y;      // 0..3
    const int tid = threadIdx.x;

    {
        int bid = blockIdx.y * 144 + blockIdx.x;
        if (bid < 45) blog[bid * 256 + tid] = 0.f;
    }

    __shared__ unsigned short sh[64][65];

#pragma unroll
    for (int j = 0; j < 4; ++j) {
        int q     = j * 256 + tid;
        int b_loc = q >> 4;
        int kq    = (q & 15) * 4;
        float4 g = *(const float4*)&inp[(size_t)(bt * 64 + b_loc) * KTOT + kt * 64 + kq];
        unsigned short h0 = f2bf(g.x), h1 = f2bf(g.y), h2 = f2bf(g.z), h3 = f2bf(g.w);
        sh[kq][b_loc] = h0; sh[kq + 1][b_loc] = h1;
        sh[kq + 2][b_loc] = h2; sh[kq + 3][b_loc] = h3;
        short4 pk = { (short)h0, (short)h1, (short)h2, (short)h3 };
        *(short4*)&inpb[(size_t)(bt * 64 + b_loc) * KTOT + kt * 64 + kq] = pk;
    }
    __syncthreads();

#pragma unroll
    for (int j = 0; j < 4; ++j) {
        int q     = j * 256 + tid;
        int k_loc = q >> 4;
        int b4    = (q & 15) * 4;
        short4 pk = { (short)sh[k_loc][b4],     (short)sh[k_loc][b4 + 1],
                      (short)sh[k_loc][b4 + 2], (short)sh[k_loc][b4 + 3] };
        *(short4*)&inpT[(size_t)(kt * 64 + k_loc) * 256 + bt * 64 + b4] = pk;
    }
}

// ---- s-pass via MFMA, softmax+Wc fused in-block -------------------------
// grid 640: bid -> nt (o), ks, mtg. 4 waves share c-scaled B tile in LDS.
#define BLP 584   // B-tile row pitch in shorts (576 + 8 pad)
__global__ __launch_bounds__(256) void spass_kernel(
    const unsigned short* __restrict__ inpb,  // [256][9216]
    const float* __restrict__ W,              // [1152][10][16][8]
    const float* __restrict__ blog,           // [1152][10]
    float* __restrict__ part)                 // [16][256][160]
{
    const int bid  = blockIdx.x;
    const int nt   = bid % 10;           // output capsule o
    const int ks   = (bid / 10) % 16;    // k-split
    const int mtg  = bid / 160;          // 0..3
    const int tid  = threadIdx.x;
    const int w    = tid >> 6;           // wave 0..3
    const int lane = tid & 63;
    const int l15  = lane & 15;
    const int koff = (lane >> 4) * 8;
    const int k0   = ks * 576;
    const int i0   = ks * 72;
    const int mt   = mtg * 4 + w;

    __shared__ unsigned short Bl[16 * BLP];   // 18.7 KB
    __shared__ float c_loc[72];

    // softmax (column nt only) for this block's 72 input capsules
    if (tid < 72) {
        const float* br = &blog[(size_t)(i0 + tid) * OC];
        float x[OC], m = -1e30f;
#pragma unroll
        for (int o = 0; o < OC; ++o) { x[o] = br[o]; m = fmaxf(m, x[o]); }
        float ssum = 0.f;
#pragma unroll
        for (int o = 0; o < OC; ++o) ssum += expf(x[o] - m);
        c_loc[tid] = expf(x[nt] - m) / ssum;
    }
    __syncthreads();

    // build c-scaled bf16 B tile: Bl[u][i_loc*8 + k] = c[i]*W[i][nt][u][k]
#pragma unroll
    for (int jj = 0; jj < 5; ++jj) {
        int q = jj * 256 + tid;          // (i_loc, u) pairs: 72*16 = 1152
        if (q < 1152) {
            int i_loc = q >> 4, u = q & 15;
            const float* wr = W + (((size_t)(i0 + i_loc) * OC + nt) * OU + u) * IK;
            float4 a = *(const float4*)wr;
            float4 b = *(const float4*)(wr + 4);
            float cc = c_loc[i_loc];
            union { short8 v; unsigned short us[8]; } pk;
            pk.us[0] = f2bf(cc * a.x); pk.us[1] = f2bf(cc * a.y);
            pk.us[2] = f2bf(cc * a.z); pk.us[3] = f2bf(cc * a.w);
            pk.us[4] = f2bf(cc * b.x); pk.us[5] = f2bf(cc * b.y);
            pk.us[6] = f2bf(cc * b.z); pk.us[7] = f2bf(cc * b.w);
            *(short8*)&Bl[u * BLP + i_loc * 8] = pk.v;
        }
    }
    __syncthreads();

    const unsigned short* ap  = inpb + (size_t)(mt * 16 + l15) * KTOT + k0 + koff;
    const unsigned short* bls = &Bl[l15 * BLP + koff];

    f32x4 acc = {0.f, 0.f, 0.f, 0.f};
#pragma unroll
    for (int kk = 0; kk < 18; ++kk) {
        short8 av = *(const short8*)(ap + kk * 32);
        short8 bv = *(const short8*)(bls + kk * 32);
        acc = __builtin_amdgcn_mfma_f32_16x16x32_bf16(av, bv, acc, 0, 0, 0);
    }

    float* pp = part + ((size_t)ks * NB + mt * 16 + (lane >> 4) * 4) * NTOT + nt * 16 + l15;
#pragma unroll
    for (int r = 0; r < 4; ++r)
        pp[(size_t)r * NTOT] = acc[r];
}

// ---- reduce partials + squash -> v (fp32) and vT (bf16, transposed) ------
__global__ __launch_bounds__(256) void reduce_squash_kernel(
    const float* __restrict__ part, float* __restrict__ vout,
    unsigned short* __restrict__ vT)   // [160][256]
{
    const int tid = threadIdx.x;
    const int el  = tid & 31;
    const int kl  = tid >> 5;        // 0..7
    const int e   = blockIdx.x * 32 + el;

    float a = part[(size_t)(kl * 2) * (NB * NTOT) + e]
            + part[(size_t)(kl * 2 + 1) * (NB * NTOT) + e];

    __shared__ float red[8][36];
    red[kl][el] = a;
    __syncthreads();

    if (tid < 32) {
        float s = ((red[0][el] + red[1][el]) + (red[2][el] + red[3][el]))
                + ((red[4][el] + red[5][el]) + (red[6][el] + red[7][el]));
        float sq = s * s;
        sq += __shfl_xor(sq, 1);
        sq += __shfl_xor(sq, 2);
        sq += __shfl_xor(sq, 4);
        sq += __shfl_xor(sq, 8);
        float vv = s * (sq / ((1.f + sq) * sqrtf(sq + 1e-9f)));
        vout[e] = vv;
        int n = e % NTOT, b = e / NTOT;
        vT[(size_t)n * 256 + b] = f2bf(vv);
    }
}

// ---- delta via MFMA: G[ik][ou] = sum_b inpT[ik][b]*vT[ou][b], fused W-contraction
__global__ __launch_bounds__(256) void delta_kernel(
    const unsigned short* __restrict__ inpT,  // [9216][256]
    const unsigned short* __restrict__ vT,    // [160][256]
    const float* __restrict__ W,              // [1152][10][16][8]
    float* __restrict__ blog)                 // [1152][10] accum
{
    const int g    = blockIdx.x * 4 + (threadIdx.x >> 6);
    const int lane = threadIdx.x & 63;
    const int mt   = g % 576;
    const int nt   = g / 576;           // = o
    const int l15  = lane & 15;
    const int quad = lane >> 4;
    const int koff = quad * 8;

    const unsigned short* ap = inpT + (size_t)(mt * 16 + l15) * 256 + koff;
    const unsigned short* bp = vT   + (size_t)(nt * 16 + l15) * 256 + koff;

    f32x4 acc = {0.f, 0.f, 0.f, 0.f};
#pragma unroll
    for (int kk = 0; kk < 8; ++kk) {
        short8 av = *(const short8*)(ap + kk * 32);
        short8 bv = *(const short8*)(bp + kk * 32);
        acc = __builtin_amdgcn_mfma_f32_16x16x32_bf16(av, bv, acc, 0, 0, 0);
    }

    const int i = mt * 2 + (quad >> 1);
    const float* wr = W + (((size_t)i * OC + nt) * OU + l15) * IK + (quad & 1) * 4;
    float4 wf = *(const float4*)wr;
    float wsum = wf.x * acc[0] + wf.y * acc[1] + wf.z * acc[2] + wf.w * acc[3];

    wsum += __shfl_xor(wsum, 16);
    wsum += __shfl_xor(wsum, 1);
    wsum += __shfl_xor(wsum, 2);
    wsum += __shfl_xor(wsum, 4);
    wsum += __shfl_xor(wsum, 8);

    if ((lane & 31) == 0)
        blog[(size_t)i * OC + nt] += wsum * (1.0f / NB);
}

extern "C" void kernel_launch(void* const* d_in, const int* in_sizes, int n_in,
                              void* d_out, int out_size, void* d_ws, size_t ws_size,
                              hipStream_t stream) {
    const float* inp = (const float*)d_in[0];   // [256][1152][8]
    const float* W   = (const float*)d_in[1];   // [1152][10][16][8]
    float* vout = (float*)d_out;                // [256][10][16]

    float* blog = (float*)d_ws;                              // 11,520 f
    float* part = blog + IC * OC;                            // 655,360 f
    unsigned short* inpb = (unsigned short*)(part + (size_t)S_KS * NB * NTOT);
    unsigned short* inpT = inpb + (size_t)NB * KTOT;         // 2,359,296 u16
    unsigned short* vT   = inpT + (size_t)KTOT * 256;        // 40,960 u16

    prep_kernel<<<dim3(144, 4), dim3(256), 0, stream>>>(inp, blog, inpb, inpT);

    for (int t = 0; t < 3; ++t) {
        spass_kernel<<<dim3(640), dim3(256), 0, stream>>>(inpb, W, blog, part);
        reduce_squash_kernel<<<dim3(NB * NTOT / 32), dim3(256), 0, stream>>>(part, vout, vT);
        if (t < 2)   // final-iteration b update is dead code in the reference
            delta_kernel<<<dim3(1440), dim3(256), 0, stream>>>(inpT, vT, W, blog);
    }
}